// Round 14
// baseline (284.028 us; speedup 1.0000x reference)
//
#include <hip/hip_runtime.h>

#define NROWS 262144
#define NE 5
#define CAP 57344                 // per-expert capacity (mean 52429, ~24 sigma)
#define NCH 4096                  // 64-row chunks (matches l1 blocks)
#define BPE2 102                  // l2 blocks per expert (510 total)
#define CHUNK 256                 // rows per l2 block-iteration (8 waves x 32)
#define CPAD 16                   // counter stride in ints

typedef __attribute__((ext_vector_type(8))) short short8;
typedef __attribute__((ext_vector_type(8))) unsigned short ushort8;
typedef __attribute__((ext_vector_type(4))) float f32x4;

__device__ __forceinline__ unsigned short f2bf(float x) {
  unsigned u = __float_as_uint(x);
  u += 0x7FFF + ((u >> 16) & 1);   // round-to-nearest-even
  return (unsigned short)(u >> 16);
}
__device__ __forceinline__ int eclass(float t) {
  return (t >= 0.2f) + (t >= 0.4f) + (t >= 0.6f) + (t >= 0.8f);
}

// ---- kernel 1: W1,W2 -> bf16 in the SWIZZLED fragment layout ---------------
// Per expert: 16384 ushorts W1 then 16384 W2. Element (col j, k) at byte
// ((j*256 + k*2) ^ ((j&7)<<4)) within its layer. Read as 16B short8 frags
// either from LDS (l2) or straight from global/L3 (l1).
__global__ __launch_bounds__(256) void convw(const float* __restrict__ W1,
                                             const float* __restrict__ W2,
                                             unsigned short* __restrict__ Wswz) {
  int idx = blockIdx.x * 256 + threadIdx.x;       // 0 .. 163839
  int which = idx / 81920;
  int rem = idx % 81920;
  int e = rem / 16384;
  int jk = rem % 16384;
  int j = jk >> 7;                // output col
  int k = jk & 127;               // k index
  const float* W = which ? W2 : W1;
  int byteoff = (j * 256 + k * 2) ^ ((j & 7) << 4);
  Wswz[(size_t)e * 32768 + which * 16384 + (byteoff >> 1)] =
      f2bf(W[(size_t)e * 16384 + k * 128 + j]);
}

// ---- kernel A: extract t + per-64-row-chunk expert histogram ---------------
__global__ __launch_bounds__(256) void thist(const float* __restrict__ x,
                                             float* __restrict__ tcomp,
                                             int* __restrict__ hist) {
  __shared__ int hS[4][NE];
  int tid = threadIdx.x;
  int r = blockIdx.x * 256 + tid;
  if (tid < 20) hS[tid / NE][tid % NE] = 0;
  float t = x[(size_t)r * 129];
  int e = eclass(t);
  tcomp[r] = t;
  __syncthreads();
  atomicAdd(&hS[tid >> 6][e], 1);
  __syncthreads();
  if (tid < 20) {
    int sub = tid / NE, ee = tid % NE;
    hist[ee * NCH + blockIdx.x * 4 + sub] = hS[sub][ee];
  }
}

// ---- kernel B: parallel exclusive prefix per expert (5 blocks x 256) -------
__global__ __launch_bounds__(256) void scan(const int* __restrict__ hist,
                                            int* __restrict__ boff,
                                            int* __restrict__ cnt) {
  __shared__ int wsum[4];
  int e = blockIdx.x;
  int tid = threadIdx.x;
  int lane = tid & 63, wv = tid >> 6;

  int v[16];
  int s = 0;
  const int* h = hist + e * NCH + tid * 16;
#pragma unroll
  for (int j = 0; j < 16; ++j) { v[j] = h[j]; s += v[j]; }

  int sc = s;
#pragma unroll
  for (int off = 1; off < 64; off <<= 1) {
    int nv = __shfl_up(sc, off);
    if (lane >= off) sc += nv;
  }
  if (lane == 63) wsum[wv] = sc;
  __syncthreads();
  int wexc = 0;
  for (int k = 0; k < wv; ++k) wexc += wsum[k];
  int run = wexc + sc - s;
  int* bo = boff + e * NCH + tid * 16;
#pragma unroll
  for (int j = 0; j < 16; ++j) { bo[j] = run; run += v[j]; }
  if (tid == 255) cnt[e * CPAD] = run;
}

// ---- kernel C (l1): stage 64 rows + block-local sort + LAYER-1 MFMA --------
// Coalesced f32 stage into bank-XOR'd [64][128] LDS + tS; classify ranks via
// wave-0 LDS atomics; per-wave 32-row tiles run layer 1 with W1 fragments
// from L3-hot Wswz; h1 (bf16) written COMPACTED to h1c + tcb/ridb.
__global__ __launch_bounds__(256, 3) void l1(
    const float* __restrict__ x, const float* __restrict__ tcomp,
    const int* __restrict__ boff, const unsigned short* __restrict__ Wswz,
    const float* __restrict__ tw1, const float* __restrict__ b1,
    float* __restrict__ tcb, int* __restrict__ ridb,
    unsigned short* __restrict__ h1c) {
  __shared__ float xf[64 * 128];    // 32KB, dword-col XOR'd by row
  __shared__ float tS[64];
  __shared__ int permS[64];
  __shared__ int cntS[NE];
  __shared__ int offS[NE];
  __shared__ int tileE[8], tileB[8], tileN[8];
  __shared__ int ntS;

  int tid = threadIdx.x;
  int blk = blockIdx.x;
  int r0 = blk * 64;

  if (tid < NE) cntS[tid] = 0;

  float t = 0.f;
  if (tid < 64) t = tcomp[r0 + tid];            // issued before stage loads

  // stage: 2064 f32x4 coalesced (base 16B-aligned: 33024 % 16 == 0),
  // elementwise scatter via magic-div 129; col0 -> tS, cols 1.. -> xf XOR'd.
  const f32x4* xv = (const f32x4*)(x + (size_t)r0 * 129);
#pragma unroll
  for (int q = 0; q < 9; ++q) {
    int v = q * 256 + tid;
    if (q < 8 || tid < 16) {
      f32x4 val = xv[v];
#pragma unroll
      for (int j = 0; j < 4; ++j) {
        int l = v * 4 + j;
        int row = (int)(((unsigned)l * 65028u) >> 23);   // l / 129
        int c = l - row * 129;
        if (c == 0) tS[row] = val[j];
        else        xf[row * 128 + ((c - 1) ^ ((row & 7) << 2))] = val[j];
      }
    }
  }

  // classify ranks (wave 0 only: cntS init + atomics same-wave ordered)
  int myE = 0, myL = 0;
  if (tid < 64) {
    myE = eclass(t);
    myL = atomicAdd(&cntS[myE], 1);
  }
  __syncthreads();                               // stage + ranks complete

  if (tid == 0) {
    int off = 0, nt = 0;
    for (int e = 0; e < NE; ++e) {
      offS[e] = off;
      int ne = cntS[e];
      for (int s = 0; s < ne; s += 32) {
        tileE[nt] = e; tileB[nt] = off + s; tileN[nt] = min(32, ne - s); ++nt;
      }
      off += ne;
    }
    ntS = nt;
  }
  __syncthreads();

  if (tid < 64) {
    permS[offS[myE] + myL] = tid;
    int d = myE * CAP + min(boff[myE * NCH + blk] + myL, CAP - 1);
    tcb[d] = t;
    ridb[d] = r0 + tid;
  }
  __syncthreads();

  int numTiles = ntS;
  int wave = tid >> 6;
  int lane = tid & 63;
  int lr = lane & 15;
  int lq = lane >> 4;

  for (int ti = wave; ti < numTiles; ti += 4) {
    int e  = tileE[ti];
    int tb = tileB[ti];
    int tn = tileN[ti];
    int d0 = e * CAP + min(boff[e * NCH + blk] + (tb - offS[e]), CAP - 64);

    int p0 = permS[tb + min(lr, tn - 1)];
    int p1 = permS[tb + min(16 + lr, tn - 1)];

    // A fragments: two aligned float4 LDS reads per ks per row, cvt to bf16
    short8 a0[4], a1[4];
#pragma unroll
    for (int ks = 0; ks < 4; ++ks) {
      int cbase = ks * 32 + lq * 8;
      f32x4 u0 = *(const f32x4*)(xf + p0 * 128 + (cbase ^ ((p0 & 7) << 2)));
      f32x4 u1 = *(const f32x4*)(xf + p0 * 128 + ((cbase + 4) ^ ((p0 & 7) << 2)));
      f32x4 w0 = *(const f32x4*)(xf + p1 * 128 + (cbase ^ ((p1 & 7) << 2)));
      f32x4 w1 = *(const f32x4*)(xf + p1 * 128 + ((cbase + 4) ^ ((p1 & 7) << 2)));
#pragma unroll
      for (int j = 0; j < 4; ++j) {
        a0[ks][j]     = (short)f2bf(u0[j]);
        a0[ks][4 + j] = (short)f2bf(u1[j]);
        a1[ks][j]     = (short)f2bf(w0[j]);
        a1[ks][4 + j] = (short)f2bf(w1[j]);
      }
    }

    int pd0[4], pd1[4];
    float t0[4], t1[4];
#pragma unroll
    for (int rr = 0; rr < 4; ++rr) {
      pd0[rr] = permS[tb + min(lq * 4 + rr, tn - 1)];
      pd1[rr] = permS[tb + min(16 + lq * 4 + rr, tn - 1)];
      t0[rr] = tS[pd0[rr]];
      t1[rr] = tS[pd1[rr]];
    }

    const char* w1p = (const char*)Wswz + (size_t)e * 65536;   // W1 half

#pragma unroll
    for (int ct = 0; ct < 8; ++ct) {
      int col = ct * 16 + lr;
      short8 b[4];
#pragma unroll
      for (int ks = 0; ks < 4; ++ks) {
        int bo = (col * 256 + ks * 64 + lq * 16) ^ ((lr & 7) << 4);
        b[ks] = *(const short8*)(w1p + bo);
      }
      f32x4 acc0 = {0.f, 0.f, 0.f, 0.f};
      f32x4 acc1 = {0.f, 0.f, 0.f, 0.f};
#pragma unroll
      for (int ks = 0; ks < 4; ++ks) {
        acc0 = __builtin_amdgcn_mfma_f32_16x16x32_bf16(a0[ks], b[ks], acc0, 0, 0, 0);
        acc1 = __builtin_amdgcn_mfma_f32_16x16x32_bf16(a1[ks], b[ks], acc1, 0, 0, 0);
      }
      float twv = tw1[e * 128 + col];
      float bv  = b1[e * 128 + col];
#pragma unroll
      for (int rr = 0; rr < 4; ++rr) {
        int s0 = lq * 4 + rr;
        int s1 = s0 + 16;
        float v0 = fmaxf(acc0[rr] + t0[rr] * twv + bv, 0.f);
        float v1 = fmaxf(acc1[rr] + t1[rr] * twv + bv, 0.f);
        if (s0 < tn) h1c[(size_t)(d0 + s0) * 128 + col] = f2bf(v0);
        if (s1 < tn) h1c[(size_t)(d0 + s1) * 128 + col] = f2bf(v1);
      }
    }
  }
}

// ---- kernel D (l2): layers 2+3; W2 in 32KB LDS, h1c read coalesced ---------
// 512 threads, LDS 32KB -> 2 blocks/CU (16 waves): 2x the old mlp's TLP.
__global__ __launch_bounds__(512, 4) void l2(
    const unsigned short* __restrict__ h1c, const float* __restrict__ tcb,
    const int* __restrict__ ridb, const int* __restrict__ cnt,
    const unsigned short* __restrict__ Wswz,
    const float* __restrict__ tw2, const float* __restrict__ b2,
    const float* __restrict__ W3, const float* __restrict__ tw3,
    const float* __restrict__ b3, float* __restrict__ out) {
  __shared__ unsigned short wl[16384];          // 32 KB: W2 swizzled

  int tid = threadIdx.x;
  int e = blockIdx.x / BPE2;
  int bi = blockIdx.x % BPE2;
  int n = min(cnt[e * CPAD], CAP);

  {
    const ushort8* wsrc = (const ushort8*)(Wswz + (size_t)e * 32768 + 16384);
    ushort8* wdst = (ushort8*)wl;
#pragma unroll
    for (int i = 0; i < 4; ++i) wdst[i * 512 + tid] = wsrc[i * 512 + tid];
  }
  __syncthreads();

  int wave = tid >> 6;
  int lane = tid & 63;
  int lr = lane & 15;
  int lq = lane >> 4;

  const char* wp2 = (const char*)wl;
  const unsigned short* hce = h1c + (size_t)e * CAP * 128;
  const float* tce = tcb + (size_t)e * CAP;
  const int* ride = ridb + (size_t)e * CAP;

  int nchunk = (n + CHUNK - 1) / CHUNK;

  auto loada = [&](int cc, short8 (&pa0)[4], short8 (&pa1)[4],
                   float& ptv, int& prv) {
    int base = cc * CHUNK + wave * 32;
    int ci = min(base + (lane & 31), n - 1);
    ptv = tce[ci];
    prv = ride[ci];
    int row0 = min(base + lr, n - 1);
    int row1 = min(base + 16 + lr, n - 1);
#pragma unroll
    for (int ks = 0; ks < 4; ++ks) {
      pa0[ks] = *(const short8*)(hce + (size_t)row0 * 128 + ks * 32 + lq * 8);
      pa1[ks] = *(const short8*)(hce + (size_t)row1 * 128 + ks * 32 + lq * 8);
    }
  };

  short8 a0[4], a1[4];
  float tv; int rv;
  int c = bi;
  if (c < nchunk) loada(c, a0, a1, tv, rv);

  for (; c < nchunk; ) {
    int cn = c + BPE2;
    bool hn = (cn < nchunk);
    short8 na0[4], na1[4];
    float ntv = 0.f; int nrv = 0;
    if (hn) loada(cn, na0, na1, ntv, nrv);      // in flight across compute

    int base = c * CHUNK + wave * 32;

    float t0[4], t1[4];
    int ro0[4], ro1[4];
#pragma unroll
    for (int rr = 0; rr < 4; ++rr) {
      t0[rr] = __shfl(tv, lq * 4 + rr);
      t1[rr] = __shfl(tv, 16 + lq * 4 + rr);
      ro0[rr] = __shfl(rv, lq * 4 + rr);
      ro1[rr] = __shfl(rv, 16 + lq * 4 + rr);
    }

    // ===== layer 2 + fused layer 3: o += relu(h1@W2 + t*tw2 + b2) * W3 =====
    const float* W3e = W3 + e * 128;
    float o0[4] = {0.f, 0.f, 0.f, 0.f};
    float o1[4] = {0.f, 0.f, 0.f, 0.f};
#pragma unroll
    for (int ct = 0; ct < 8; ++ct) {
      int col = ct * 16 + lr;
      short8 b[4];
#pragma unroll
      for (int ks = 0; ks < 4; ++ks) {
        int bo = (col * 256 + ks * 64 + lq * 16) ^ ((lr & 7) << 4);
        b[ks] = *(const short8*)(wp2 + bo);
      }
      f32x4 acc0 = {0.f, 0.f, 0.f, 0.f};
      f32x4 acc1 = {0.f, 0.f, 0.f, 0.f};
#pragma unroll
      for (int ks = 0; ks < 4; ++ks) {
        acc0 = __builtin_amdgcn_mfma_f32_16x16x32_bf16(a0[ks], b[ks], acc0, 0, 0, 0);
        acc1 = __builtin_amdgcn_mfma_f32_16x16x32_bf16(a1[ks], b[ks], acc1, 0, 0, 0);
      }
      float twv = tw2[e * 128 + col];
      float bv  = b2[e * 128 + col];
      float w3v = W3e[col];
#pragma unroll
      for (int rr = 0; rr < 4; ++rr) {
        float v0 = fmaxf(acc0[rr] + t0[rr] * twv + bv, 0.f);
        float v1 = fmaxf(acc1[rr] + t1[rr] * twv + bv, 0.f);
        o0[rr] += v0 * w3v;
        o1[rr] += v1 * w3v;
      }
    }

#pragma unroll
    for (int rr = 0; rr < 4; ++rr) {
      float s0 = o0[rr], s1 = o1[rr];
      s0 += __shfl_xor(s0, 1);  s1 += __shfl_xor(s1, 1);
      s0 += __shfl_xor(s0, 2);  s1 += __shfl_xor(s1, 2);
      s0 += __shfl_xor(s0, 4);  s1 += __shfl_xor(s1, 4);
      s0 += __shfl_xor(s0, 8);  s1 += __shfl_xor(s1, 8);
      o0[rr] = s0;  o1[rr] = s1;
    }

    if (lr == 0) {
      float tw3v = tw3[e];
      float b3v  = b3[e];
#pragma unroll
      for (int rr = 0; rr < 4; ++rr) {
        if (base + lq * 4 + rr < n)
          out[ro0[rr]] = o0[rr] + t0[rr] * tw3v + b3v;
        if (base + 16 + lq * 4 + rr < n)
          out[ro1[rr]] = o1[rr] + t1[rr] * tw3v + b3v;
      }
    }

    if (hn) {
#pragma unroll
      for (int ks = 0; ks < 4; ++ks) { a0[ks] = na0[ks]; a1[ks] = na1[ks]; }
      tv = ntv; rv = nrv;
    }
    c = cn;
  }
}

extern "C" void kernel_launch(void* const* d_in, const int* in_sizes, int n_in,
                              void* d_out, int out_size, void* d_ws, size_t ws_size,
                              hipStream_t stream) {
  const float* x   = (const float*)d_in[0];
  const float* W1  = (const float*)d_in[1];
  const float* tw1 = (const float*)d_in[2];
  const float* b1  = (const float*)d_in[3];
  const float* W2  = (const float*)d_in[4];
  const float* tw2 = (const float*)d_in[5];
  const float* b2  = (const float*)d_in[6];
  const float* W3  = (const float*)d_in[7];
  const float* tw3 = (const float*)d_in[8];
  const float* b3  = (const float*)d_in[9];
  float* out = (float*)d_out;

  char* ws = (char*)d_ws;
  size_t off = 0;
  int*   cnt   = (int*)(ws + off);   off += 1024;
  float* tcomp = (float*)(ws + off); off += (size_t)NROWS * 4;        // 1 MB
  int*   hist  = (int*)(ws + off);   off += (size_t)NE * NCH * 4;     // 80 KB
  int*   boff  = (int*)(ws + off);   off += (size_t)NE * NCH * 4;     // 80 KB
  int*   ridb  = (int*)(ws + off);   off += (size_t)NE * CAP * 4;
  float* tcb   = (float*)(ws + off); off += (size_t)NE * CAP * 4;
  unsigned short* h1c = (unsigned short*)(ws + off); off += (size_t)NE * CAP * 256;
  unsigned short* Wswz = (unsigned short*)(ws + off);                 // 320 KB

  convw<<<640, 256, 0, stream>>>(W1, W2, Wswz);
  thist<<<NROWS / 256, 256, 0, stream>>>(x, tcomp, hist);
  scan<<<NE, 256, 0, stream>>>(hist, boff, cnt);
  l1<<<NCH, 256, 0, stream>>>(x, tcomp, boff, Wswz, tw1, b1, tcb, ridb, h1c);
  l2<<<NE * BPE2, 512, 0, stream>>>(h1c, tcb, ridb, cnt, Wswz,
                                    tw2, b2, W3, tw3, b3, out);
}